// Round 18
// baseline (243.044 us; speedup 1.0000x reference)
//
#include <hip/hip_runtime.h>
#include <hip/hip_fp8.h>

#define N_NODES 20000
#define N_EDGES 320000
#define FF 64
#define KK 32
#define EPAD 460032   // >= 320000 + 20000*7 (CSR padded to %8), multiple of 64
#define GT 64
#define BW 8

typedef _Float16 half4v __attribute__((ext_vector_type(4)));
typedef _Float16 h2 __attribute__((ext_vector_type(2)));
typedef short bf16x8 __attribute__((ext_vector_type(8)));
typedef float fx4 __attribute__((ext_vector_type(4)));

__device__ __forceinline__ unsigned short f2bf(float x) {
    unsigned u = __float_as_uint(x);
    unsigned r = (u + 0x7FFFu + ((u >> 16) & 1u)) >> 16;
    return (unsigned short)r;
}
__device__ __forceinline__ h2 u2h(unsigned u) {
    union { unsigned u; h2 h; } c; c.u = u; return c.h;
}
__device__ __forceinline__ unsigned h2u(h2 h) {
    union { h2 h; unsigned u; } c; c.h = h; return c.u;
}
// fp8x2 (e4m3, OCP) -> h2 via HW-accelerated conversion
__device__ __forceinline__ h2 fp8pair2h(unsigned short p) {
    __half2_raw hr = __hip_cvt_fp8x2_to_halfraw2((__hip_fp8x2_storage_t)p, __HIP_E4M3);
    union { __half2_raw r; unsigned u; } cv; cv.r = hr;
    return u2h(cv.u);
}

__global__ __launch_bounds__(256) void hist_k(const int* __restrict__ dst,
                                              int* __restrict__ cnt) {
    int e = blockIdx.x * 256 + threadIdx.x;
    if (e >= N_EDGES) return;
    atomicAdd(&cnt[dst[e]], 1);
}

// Prefix-sum of PADDED counts (pad to %8): rps[n] = start, rps[N]=total padded.
__global__ __launch_bounds__(1024) void scan_k(const int* __restrict__ cnt,
                                               int* __restrict__ rps) {
    __shared__ int part[1024];
    int t = threadIdx.x;
    const int CH = 20;
    int lo = t * CH;
    int hi = lo + CH; if (hi > N_NODES) hi = N_NODES;
    int s = 0;
    for (int i = lo; i < hi && lo < N_NODES; ++i) s += (cnt[i] + 7) & ~7;
    if (lo >= N_NODES) s = 0;
    part[t] = s;
    __syncthreads();
    for (int off = 1; off < 1024; off <<= 1) {
        int tmp = (t >= off) ? part[t - off] : 0;
        __syncthreads();
        part[t] += tmp;
        __syncthreads();
    }
    int excl = part[t] - s;
    if (lo < N_NODES) {
        int run = excl;
        for (int i = lo; i < hi; ++i) { rps[i] = run; run += (cnt[i] + 7) & ~7; }
    }
    if (t == 1023) rps[N_NODES] = part[1023];
}

__global__ __launch_bounds__(256) void scatter_k(const float* __restrict__ coords,
                                                 const int* __restrict__ dst,
                                                 const int* __restrict__ src,
                                                 const int* __restrict__ rps,
                                                 int* __restrict__ fill,
                                                 int* __restrict__ esrcB,
                                                 float4* __restrict__ egeom) {
    int e = blockIdx.x * 256 + threadIdx.x;
    if (e >= N_EDGES) return;
    int di = dst[e], si = src[e];
    int pos = rps[di] + atomicAdd(&fill[di], 1);
    float rx = coords[di*3+0] - coords[si*3+0];
    float ry = coords[di*3+1] - coords[si*3+1];
    float rz = coords[di*3+2] - coords[si*3+2];
    float d = sqrtf(rx*rx + ry*ry + rz*rz + 1e-12f);
    float inv = 1.0f / d;
    esrcB[pos] = si * 512;
    egeom[pos] = make_float4(d, rx*inv, ry*inv, rz*inv);
}

// Fill padding holes with dummy edges -> zero row (A=0 => msg=0), finite geom.
__global__ __launch_bounds__(256) void pad_k(const int* __restrict__ rps,
                                             const int* __restrict__ cnt,
                                             int* __restrict__ esrcB,
                                             float4* __restrict__ egeom) {
    int n = blockIdx.x * 256 + threadIdx.x;
    if (n >= N_NODES) return;
    int fin = rps[n] + cnt[n];
    int stop = rps[n+1];
    for (int e = fin; e < stop; ++e) {
        esrcB[e] = N_NODES * 512;               // zero row
        egeom[e] = make_float4(1.f, 0.f, 0.f, 0.f);
    }
}

// Packed fp16 rhat plane, batch-major: per 8-edge batch b, 12 uints:
// [c=y,z,w][pair p=0..3], each uint = {rhat_c[8b+2p], rhat_c[8b+2p+1]}.
__global__ __launch_bounds__(256) void geomh_k(const float4* __restrict__ egeom,
                                               const int* __restrict__ rps,
                                               unsigned* __restrict__ gH) {
    int b = blockIdx.x * 256 + threadIdx.x;
    int total = rps[N_NODES];
    if (b * 8 >= total) return;
    float4 g[8];
    #pragma unroll
    for (int j = 0; j < 8; ++j) g[j] = egeom[b*8 + j];
    unsigned* o = gH + (size_t)b * 12;
    #pragma unroll
    for (int p = 0; p < 4; ++p) {
        h2 y; y[0] = (_Float16)g[2*p].y; y[1] = (_Float16)g[2*p+1].y;
        h2 z; z[0] = (_Float16)g[2*p].z; z[1] = (_Float16)g[2*p+1].z;
        h2 w; w[0] = (_Float16)g[2*p].w; w[1] = (_Float16)g[2*p+1].w;
        o[0*4 + p] = h2u(y);
        o[1*4 + p] = h2u(z);
        o[2*4 + p] = h2u(w);
    }
}

// MFMA gmat: per 64-edge tile, G[64e][64f] = rbf[64e][32k] x W[32k][64f]
// via 16x16x32 bf16 MFMA (verified R13). Output: fp8(e4m3) packed 4 edges/uint.
template<int NR>
__global__ __launch_bounds__(256) void gmatM_k(const float4* __restrict__ egeom,
                                               const float* __restrict__ Wb,
                                               const int* __restrict__ rps,
                                               unsigned* __restrict__ G8) {
    __shared__ __align__(16) short WtL[NR*KK*FF];    // 12 KB bf16, k-major
    __shared__ __align__(16) short rbfL[2][GT*40];   // 2 x 5 KB, row pad 40
    int t = threadIdx.x;
    for (int idx = t; idx < NR*KK*FF; idx += 256)
        WtL[idx] = (short)f2bf(Wb[idx]);
    __syncthreads();

    int lane = t & 63, q = t >> 6;
    int kb = lane >> 4, cl = lane & 15;

    bf16x8 Bfr[NR][4];
    #pragma unroll
    for (int r = 0; r < NR; ++r) {
        #pragma unroll
        for (int nb = 0; nb < 4; ++nb) {
            bf16x8 fr;
            #pragma unroll
            for (int e2 = 0; e2 < 8; ++e2)
                fr[e2] = WtL[r*2048 + (kb*8 + e2)*64 + nb*16 + cl];
            Bfr[r][nb] = fr;
        }
    }

    int total = rps[N_NODES];
    int ntiles = (total + GT - 1) / GT;
    const float inv_w = 31.0f / 2.5f;
    int buf = 0;
    for (int tile = blockIdx.x; tile < ntiles; tile += gridDim.x) {
        int e0 = tile * GT;
        {
            int ew = t & 63;
            float d = egeom[e0 + ew].x;
            float t0 = d * inv_w;
            int k0 = (int)floorf(t0 + 0.5f) - 4;
            if (k0 < 0) k0 = 0;
            if (k0 > KK - 9) k0 = KK - 9;
            bf16x8 pk;
            #pragma unroll
            for (int i2 = 0; i2 < 8; ++i2) {
                int j = q*8 + i2;
                float dt = t0 - (float)j;
                float v = (j >= k0 && j < k0 + 9) ? __expf(-dt * dt) : 0.f;
                pk[i2] = (short)f2bf(v);
            }
            *(bf16x8*)(&rbfL[buf][ew*40 + q*8]) = pk;
        }
        __syncthreads();
        bf16x8 afr = *(const bf16x8*)(&rbfL[buf][(q*16 + cl)*40 + kb*8]);
        int eg = (e0 + q*16 + kb*4) >> 2;
        #pragma unroll
        for (int r = 0; r < NR; ++r) {
            #pragma unroll
            for (int nb = 0; nb < 4; ++nb) {
                fx4 dacc = {0.f, 0.f, 0.f, 0.f};
                dacc = __builtin_amdgcn_mfma_f32_16x16x32_bf16(afr, Bfr[r][nb],
                                                               dacc, 0, 0, 0);
                unsigned b0 = (unsigned)__hip_cvt_float_to_fp8(dacc[0], __HIP_SATFINITE, __HIP_E4M3);
                unsigned b1 = (unsigned)__hip_cvt_float_to_fp8(dacc[1], __HIP_SATFINITE, __HIP_E4M3);
                unsigned b2 = (unsigned)__hip_cvt_float_to_fp8(dacc[2], __HIP_SATFINITE, __HIP_E4M3);
                unsigned b3 = (unsigned)__hip_cvt_float_to_fp8(dacc[3], __HIP_SATFINITE, __HIP_E4M3);
                unsigned word = b0 | (b1 << 8) | (b2 << 16) | (b3 << 24);
                G8[(size_t)r*(EPAD/4)*64 + (size_t)eg*64 + nb*16 + cl] = word;
            }
        }
        buf ^= 1;
    }
}

// MFMA node_in: one wave per 16-node tile (verified R14).
__global__ __launch_bounds__(256) void node_inM_k(const float* __restrict__ x_dftb,
                                                  const float* __restrict__ W0,
                                                  const float* __restrict__ W1,
                                                  const float* __restrict__ bin,
                                                  float* __restrict__ x,
                                                  half4v* __restrict__ xh) {
    int t = threadIdx.x;
    int q = t >> 6, lane = t & 63;
    int kb = lane >> 4, cl = lane & 15;
    int w = blockIdx.x * 4 + q;
    if (w >= N_NODES / 16) return;
    int n0 = w * 16;

    bf16x8 BF[2][4][2];
    #pragma unroll
    for (int cb = 0; cb < 4; ++cb) {
        #pragma unroll
        for (int kf = 0; kf < 2; ++kf) {
            bf16x8 f0, f1;
            #pragma unroll
            for (int j = 0; j < 8; ++j) {
                int k = kf*32 + kb*8 + j;
                f0[j] = (short)f2bf(W0[k*64 + cb*16 + cl]);
                f1[j] = (short)f2bf(W1[k*64 + cb*16 + cl]);
            }
            BF[0][cb][kf] = f0;
            BF[1][cb][kf] = f1;
        }
    }
    float bb[4];
    #pragma unroll
    for (int cb = 0; cb < 4; ++cb) bb[cb] = bin[cb*16 + cl];

    fx4 acc[4][4];   // [l][cb]
    #pragma unroll
    for (int l = 0; l < 4; ++l) {
        const float* xr = x_dftb + (size_t)(n0 + cl)*256 + l*64 + kb*8;
        float4 v0 = *(const float4*)(xr);
        float4 v1 = *(const float4*)(xr + 4);
        float4 v2 = *(const float4*)(xr + 32);
        float4 v3 = *(const float4*)(xr + 36);
        bf16x8 a0, a1;
        a0[0]=(short)f2bf(v0.x); a0[1]=(short)f2bf(v0.y);
        a0[2]=(short)f2bf(v0.z); a0[3]=(short)f2bf(v0.w);
        a0[4]=(short)f2bf(v1.x); a0[5]=(short)f2bf(v1.y);
        a0[6]=(short)f2bf(v1.z); a0[7]=(short)f2bf(v1.w);
        a1[0]=(short)f2bf(v2.x); a1[1]=(short)f2bf(v2.y);
        a1[2]=(short)f2bf(v2.z); a1[3]=(short)f2bf(v2.w);
        a1[4]=(short)f2bf(v3.x); a1[5]=(short)f2bf(v3.y);
        a1[6]=(short)f2bf(v3.z); a1[7]=(short)f2bf(v3.w);
        const int wsel = (l == 0) ? 0 : 1;
        #pragma unroll
        for (int cb = 0; cb < 4; ++cb) {
            fx4 c = {0.f, 0.f, 0.f, 0.f};
            c = __builtin_amdgcn_mfma_f32_16x16x32_bf16(a0, BF[wsel][cb][0], c, 0, 0, 0);
            c = __builtin_amdgcn_mfma_f32_16x16x32_bf16(a1, BF[wsel][cb][1], c, 0, 0, 0);
            acc[l][cb] = c;
        }
    }

    #pragma unroll
    for (int cb = 0; cb < 4; ++cb) {
        int f = cb*16 + cl;
        #pragma unroll
        for (int reg = 0; reg < 4; ++reg) {
            int n = n0 + kb*4 + reg;
            float a0v = acc[0][cb][reg] + bb[cb];
            float a1v = acc[1][cb][reg];
            float a2v = acc[2][cb][reg];
            float a3v = acc[3][cb][reg];
            *(float4*)(x + (size_t)n*256 + f*4) = make_float4(a0v, a1v, a2v, a3v);
            half4v hs;
            hs[0] = (_Float16)a0v; hs[1] = (_Float16)a1v;
            hs[2] = (_Float16)a2v; hs[3] = (_Float16)a3v;
            xh[(size_t)n*64 + f] = hs;
        }
    }
}

// Scalar node_in (fallback when no fp16 shadow / tiny ws).
__global__ __launch_bounds__(256) void node_in_k(const float* __restrict__ x_dftb,
                                                 const float* __restrict__ W0,
                                                 const float* __restrict__ W1,
                                                 const float* __restrict__ bin,
                                                 float* __restrict__ x,
                                                 half4v* __restrict__ xh) {
    int t = threadIdx.x;
    int q = t >> 6, f = t & 63;
    int n = blockIdx.x * 4 + q;
    float w0r[64], w1r[64];
    #pragma unroll
    for (int k = 0; k < 64; ++k) { w0r[k] = W0[k*64 + f]; w1r[k] = W1[k*64 + f]; }
    float a0 = bin[f], a1 = 0.f, a2 = 0.f, a3 = 0.f;
    const float4* xr = (const float4*)(x_dftb + (size_t)n * 256);
    #pragma unroll
    for (int j = 0; j < 16; ++j) {
        float4 x0 = xr[j];
        float4 x1 = xr[16 + j];
        float4 x2 = xr[32 + j];
        float4 x3 = xr[48 + j];
        a0 += x0.x*w0r[4*j] + x0.y*w0r[4*j+1] + x0.z*w0r[4*j+2] + x0.w*w0r[4*j+3];
        a1 += x1.x*w1r[4*j] + x1.y*w1r[4*j+1] + x1.z*w1r[4*j+2] + x1.w*w1r[4*j+3];
        a2 += x2.x*w1r[4*j] + x2.y*w1r[4*j+1] + x2.z*w1r[4*j+2] + x2.w*w1r[4*j+3];
        a3 += x3.x*w1r[4*j] + x3.y*w1r[4*j+1] + x3.z*w1r[4*j+2] + x3.w*w1r[4*j+3];
    }
    *(float4*)(x + (size_t)n*256 + f*4) = make_float4(a0, a1, a2, a3);
    if (xh) {
        half4v hs;
        hs[0] = (_Float16)a0; hs[1] = (_Float16)a1;
        hs[2] = (_Float16)a2; hs[3] = (_Float16)a3;
        xh[(size_t)n*64 + f] = hs;
    }
}

// One wave per dst node, lane = feature. Packed fp16 math (R16, verified).
// G plane in fp8 e4m3, 4 edges/uint; decoded pairwise via HW cvt.
// 16-edge batches + 8-edge remainder. LAST=1: fuse node_out.
template<int LAST>
__global__ __launch_bounds__(256) void msg_pk_k(const int* __restrict__ rps,
                                                const int* __restrict__ esrcB,
                                                const unsigned* __restrict__ gH,
                                                const unsigned* __restrict__ G8,
                                                const float* __restrict__ bbv,
                                                const float* __restrict__ pw,
                                                const float* __restrict__ xo_f,
                                                const half4v* __restrict__ xo_h,
                                                float* __restrict__ xn_f,
                                                half4v* __restrict__ xn_h,
                                                const float* __restrict__ Wo0,
                                                const float* __restrict__ Wo1,
                                                const float* __restrict__ bo,
                                                float* __restrict__ out) {
    int t = threadIdx.x;
    int q = t >> 6, f = t & 63;
    int n = blockIdx.x * 4 + q;

    float4 self = *(const float4*)(xo_f + (size_t)n*256 + f*4);
    float acc0 = self.x, acc1 = self.y, acc2 = self.z, acc3 = self.w;

    float b_f = bbv[f];
    _Float16 bh = (_Float16)b_f;
    _Float16 p0h = (_Float16)pw[f],      p1h = (_Float16)pw[64+f];
    _Float16 p2h = (_Float16)pw[128+f],  p3h = (_Float16)pw[192+f];
    _Float16 p4h = (_Float16)pw[256+f];
    h2 pb;  pb[0]=bh;  pb[1]=bh;
    h2 pp0; pp0[0]=p0h; pp0[1]=p0h;
    h2 pp1; pp1[0]=p1h; pp1[1]=p1h;
    h2 pp2; pp2[0]=p2h; pp2[1]=p2h;
    h2 pp3; pp3[0]=p3h; pp3[1]=p3h;
    h2 pp4; pp4[0]=p4h; pp4[1]=p4h;

    const char* xob = (const char*)xo_h;
    int fb = f * 8;
    int beg = rps[n], end = rps[n+1];
    int e0 = beg;

    // 16-edge main loop: all loads hoisted (max MLP)
    for (; e0 + 16 <= end; e0 += 16) {
        int4 o0 = *(const int4*)(esrcB + e0);
        int4 o1 = *(const int4*)(esrcB + e0 + 4);
        int4 o2 = *(const int4*)(esrcB + e0 + 8);
        int4 o3 = *(const int4*)(esrcB + e0 + 12);
        int off[16] = {o0.x,o0.y,o0.z,o0.w, o1.x,o1.y,o1.z,o1.w,
                       o2.x,o2.y,o2.z,o2.w, o3.x,o3.y,o3.z,o3.w};
        half4v h[16];
        #pragma unroll
        for (int j = 0; j < 16; ++j)
            h[j] = *(const half4v*)(xob + (size_t)(unsigned)off[j] + fb);
        unsigned g0w = G8[(size_t)(e0 >> 2)*64 + f];
        unsigned g1w = G8[(size_t)((e0 >> 2)+1)*64 + f];
        unsigned g2w = G8[(size_t)((e0 >> 2)+2)*64 + f];
        unsigned g3w = G8[(size_t)((e0 >> 2)+3)*64 + f];
        unsigned short gp8[8] = {
            (unsigned short)(g0w & 0xffff), (unsigned short)(g0w >> 16),
            (unsigned short)(g1w & 0xffff), (unsigned short)(g1w >> 16),
            (unsigned short)(g2w & 0xffff), (unsigned short)(g2w >> 16),
            (unsigned short)(g3w & 0xffff), (unsigned short)(g3w >> 16)};
        const unsigned* gb_ = gH + (size_t)(e0 >> 3) * 12;
        uint4 gy0 = *(const uint4*)(gb_);
        uint4 gz0 = *(const uint4*)(gb_ + 4);
        uint4 gw0 = *(const uint4*)(gb_ + 8);
        uint4 gy1 = *(const uint4*)(gb_ + 12);
        uint4 gz1 = *(const uint4*)(gb_ + 16);
        uint4 gw1 = *(const uint4*)(gb_ + 20);
        unsigned gyu[8] = {gy0.x,gy0.y,gy0.z,gy0.w, gy1.x,gy1.y,gy1.z,gy1.w};
        unsigned gzu[8] = {gz0.x,gz0.y,gz0.z,gz0.w, gz1.x,gz1.y,gz1.z,gz1.w};
        unsigned gwu[8] = {gw0.x,gw0.y,gw0.z,gw0.w, gw1.x,gw1.y,gw1.z,gw1.w};

        h2 s0, s1, s2, s3;
        s0[0]=(_Float16)0; s0[1]=(_Float16)0; s1 = s0; s2 = s0; s3 = s0;

        #pragma unroll
        for (int i = 0; i < 8; ++i) {
            h2 a0; a0[0] = h[2*i][0]; a0[1] = h[2*i+1][0];
            h2 a1; a1[0] = h[2*i][1]; a1[1] = h[2*i+1][1];
            h2 a2; a2[0] = h[2*i][2]; a2[1] = h[2*i+1][2];
            h2 a3; a3[0] = h[2*i][3]; a3[1] = h[2*i+1][3];
            h2 G  = fp8pair2h(gp8[i]);
            h2 ry = u2h(gyu[i]);
            h2 rz = u2h(gzu[i]);
            h2 rw = u2h(gwu[i]);

            h2 g0v = G + pb;
            h2 dot = a1*ry + a2*rz + a3*rw;
            s0 += pp0*a0*g0v + pp1*dot*G;
            h2 tA = pp2*a0*G;
            h2 tB = pp3*g0v;
            h2 tC = pp4*G;
            s1 += tA*ry + tB*a1 + tC*(a2*rw - a3*rz);
            s2 += tA*rz + tB*a2 + tC*(a3*ry - a1*rw);
            s3 += tA*rw + tB*a3 + tC*(a1*rz - a2*ry);
        }
        acc0 += (float)s0[0] + (float)s0[1];
        acc1 += (float)s1[0] + (float)s1[1];
        acc2 += (float)s2[0] + (float)s2[1];
        acc3 += (float)s3[0] + (float)s3[1];
    }

    // 8-edge remainder (0 or 1 iterations)
    if (e0 < end) {
        int4 oa = *(const int4*)(esrcB + e0);
        int4 ob = *(const int4*)(esrcB + e0 + 4);
        int off[BW] = {oa.x, oa.y, oa.z, oa.w, ob.x, ob.y, ob.z, ob.w};
        half4v h[BW];
        #pragma unroll
        for (int j = 0; j < BW; ++j)
            h[j] = *(const half4v*)(xob + (size_t)(unsigned)off[j] + fb);
        unsigned g0w = G8[(size_t)(e0 >> 2)*64 + f];
        unsigned g1w = G8[(size_t)((e0 >> 2)+1)*64 + f];
        unsigned short gp8[4] = {
            (unsigned short)(g0w & 0xffff), (unsigned short)(g0w >> 16),
            (unsigned short)(g1w & 0xffff), (unsigned short)(g1w >> 16)};
        const unsigned* gb_ = gH + (size_t)(e0 >> 3) * 12;
        uint4 gyv = *(const uint4*)(gb_);
        uint4 gzv = *(const uint4*)(gb_ + 4);
        uint4 gwv = *(const uint4*)(gb_ + 8);
        unsigned gyu[4] = {gyv.x, gyv.y, gyv.z, gyv.w};
        unsigned gzu[4] = {gzv.x, gzv.y, gzv.z, gzv.w};
        unsigned gwu[4] = {gwv.x, gwv.y, gwv.z, gwv.w};

        h2 s0, s1, s2, s3;
        s0[0]=(_Float16)0; s0[1]=(_Float16)0; s1 = s0; s2 = s0; s3 = s0;

        #pragma unroll
        for (int i = 0; i < 4; ++i) {
            h2 a0; a0[0] = h[2*i][0]; a0[1] = h[2*i+1][0];
            h2 a1; a1[0] = h[2*i][1]; a1[1] = h[2*i+1][1];
            h2 a2; a2[0] = h[2*i][2]; a2[1] = h[2*i+1][2];
            h2 a3; a3[0] = h[2*i][3]; a3[1] = h[2*i+1][3];
            h2 G  = fp8pair2h(gp8[i]);
            h2 ry = u2h(gyu[i]);
            h2 rz = u2h(gzu[i]);
            h2 rw = u2h(gwu[i]);

            h2 g0v = G + pb;
            h2 dot = a1*ry + a2*rz + a3*rw;
            s0 += pp0*a0*g0v + pp1*dot*G;
            h2 tA = pp2*a0*G;
            h2 tB = pp3*g0v;
            h2 tC = pp4*G;
            s1 += tA*ry + tB*a1 + tC*(a2*rw - a3*rz);
            s2 += tA*rz + tB*a2 + tC*(a3*ry - a1*rw);
            s3 += tA*rw + tB*a3 + tC*(a1*rz - a2*ry);
        }
        acc0 += (float)s0[0] + (float)s0[1];
        acc1 += (float)s1[0] + (float)s1[1];
        acc2 += (float)s2[0] + (float)s2[1];
        acc3 += (float)s3[0] + (float)s3[1];
    }

    if (LAST) {
        float w0 = Wo0[f], w1 = Wo1[f];
        float s0 = acc0 * w0, s1 = acc1 * w1, s2 = acc2 * w1, s3 = acc3 * w1;
        #pragma unroll
        for (int off2 = 32; off2 >= 1; off2 >>= 1) {
            s0 += __shfl_down(s0, off2, 64);
            s1 += __shfl_down(s1, off2, 64);
            s2 += __shfl_down(s2, off2, 64);
            s3 += __shfl_down(s3, off2, 64);
        }
        if (f == 0) {
            float b = bo[0];
            out[n*4 + 0] = s0 + b;
            out[n*4 + 1] = s1;
            out[n*4 + 2] = s2;
            out[n*4 + 3] = s3;
        }
    } else {
        *(float4*)(xn_f + (size_t)n*256 + f*4) = make_float4(acc0, acc1, acc2, acc3);
        half4v hs;
        hs[0] = (_Float16)acc0; hs[1] = (_Float16)acc1;
        hs[2] = (_Float16)acc2; hs[3] = (_Float16)acc3;
        xn_h[(size_t)n*64 + f] = hs;
    }
}

// Fallback (tiny ws): f32 gathers, in-kernel shfl G, real-count loop.
__global__ __launch_bounds__(256) void msg_slow_k(const int* __restrict__ rps,
                                                  const int* __restrict__ cnt,
                                                  const int* __restrict__ esrcB,
                                                  const float4* __restrict__ egeom,
                                                  const float* __restrict__ Wb,
                                                  const float* __restrict__ bbv,
                                                  const float* __restrict__ pw,
                                                  const float* __restrict__ xo_f,
                                                  float* __restrict__ xn_f) {
    int t = threadIdx.x;
    int n = blockIdx.x * 4 + (t >> 6);
    int f = t & 63;
    float wreg[KK];
    #pragma unroll
    for (int k = 0; k < KK; ++k) wreg[k] = Wb[k*64 + f];
    float4 self = *(const float4*)(xo_f + (size_t)n*256 + f*4);
    float acc0 = self.x, acc1 = self.y, acc2 = self.z, acc3 = self.w;
    float b_f = bbv[f];
    float p0 = pw[f], p1 = pw[64+f], p2 = pw[128+f], p3 = pw[192+f], p4 = pw[256+f];
    const float wdt = 2.5f / 31.0f, inv_w = 31.0f / 2.5f;
    float ck = wdt * (float)(f & 31);
    int beg = rps[n], end = beg + cnt[n];
    const char* xob = (const char*)xo_f;
    for (int e = beg; e < end; ++e) {
        int off = esrcB[e];
        float4 g4 = egeom[e];
        float4 v = *(const float4*)(xob + ((size_t)(unsigned)off << 1) + f*16);
        float tt = (g4.x - ck) * inv_w;
        float my_rbf = __expf(-tt * tt);
        float Gs = 0.f;
        #pragma unroll
        for (int k = 0; k < KK; ++k) Gs += __shfl(my_rbf, k, 64) * wreg[k];
        float g0v = Gs + b_f;
        float dotav = v.y*g4.y + v.z*g4.z + v.w*g4.w;
        acc0 += p0*v.x*g0v + p1*dotav*Gs;
        float tA = p2*v.x*Gs, tB = p3*g0v, tC = p4*Gs;
        acc1 += tA*g4.y + tB*v.y + tC*(v.z*g4.w - v.w*g4.z);
        acc2 += tA*g4.z + tB*v.z + tC*(v.w*g4.y - v.y*g4.w);
        acc3 += tA*g4.w + tB*v.w + tC*(v.y*g4.z - v.z*g4.y);
    }
    *(float4*)(xn_f + (size_t)n*256 + f*4) = make_float4(acc0, acc1, acc2, acc3);
}

__global__ __launch_bounds__(256) void node_out_k(const float* __restrict__ x,
                                                  const float* __restrict__ W0,
                                                  const float* __restrict__ W1,
                                                  const float* __restrict__ bout,
                                                  float* __restrict__ out) {
    int n = blockIdx.x * 4 + (threadIdx.x >> 6);
    int f = threadIdx.x & 63;
    float w0 = W0[f], w1 = W1[f];
    float4 v = *(const float4*)(x + (size_t)n*256 + f*4);
    float s0 = v.x * w0, s1 = v.y * w1, s2 = v.z * w1, s3 = v.w * w1;
    #pragma unroll
    for (int off = 32; off >= 1; off >>= 1) {
        s0 += __shfl_down(s0, off, 64);
        s1 += __shfl_down(s1, off, 64);
        s2 += __shfl_down(s2, off, 64);
        s3 += __shfl_down(s3, off, 64);
    }
    if (f == 0) {
        float b = bout[0];
        out[n*4 + 0] = s0 + b;
        out[n*4 + 1] = s1;
        out[n*4 + 2] = s2;
        out[n*4 + 3] = s3;
    }
}

extern "C" void kernel_launch(void* const* d_in, const int* in_sizes, int n_in,
                              void* d_out, int out_size, void* d_ws, size_t ws_size,
                              hipStream_t stream) {
    const float* x_dftb  = (const float*)d_in[0];
    const float* coords  = (const float*)d_in[1];
    const int*   dst     = (const int*)  d_in[2];
    const int*   src     = (const int*)  d_in[3];
    const float* W_in0   = (const float*)d_in[4];
    const float* W_in1   = (const float*)d_in[5];
    const float* b_in    = (const float*)d_in[6];
    const float* W_basis = (const float*)d_in[7];
    const float* b_basis = (const float*)d_in[8];
    const float* path_w  = (const float*)d_in[9];
    const float* W_out0  = (const float*)d_in[10];
    const float* W_out1  = (const float*)d_in[11];
    const float* b_out   = (const float*)d_in[12];
    float* out = (float*)d_out;

    const size_t XF = (size_t)N_NODES * 256 * 4;        // 20.48 MB
    const size_t XH = (size_t)(N_NODES + 1) * 64 * 8;   // 10.24 MB (fp16 + zero row)
    const size_t EG = (size_t)EPAD * 16;                //  7.36 MB
    const size_t ES = (size_t)EPAD * 4;                 //  1.84 MB
    const size_t GP = (size_t)EPAD * 64;                // 29.44 MB (one fp8 plane)
    const size_t GH = (size_t)(EPAD/8) * 48;            //  2.76 MB (packed rhat)
    const size_t RP = (((size_t)(N_NODES + 1) * 4) + 15) & ~(size_t)15;
    const size_t CF = (size_t)N_NODES * 4;

    const size_t base_need = 2*XF + 2*XH + EG + ES + GH + RP + 2*CF;
    int planes = (ws_size >= base_need + 3*GP) ? 3
               : (ws_size >= base_need + 1*GP) ? 1 : 0;

    char* p = (char*)d_ws;
    float*   xA = (float*)p;  p += XF;
    float*   xB = (float*)p;  p += XF;
    half4v*  hA = nullptr; half4v* hB = nullptr;
    unsigned* Gm = nullptr;
    unsigned* gH = nullptr;
    if (planes) {
        hA = (half4v*)p;  p += XH;
        hB = (half4v*)p;  p += XH;
        Gm = (unsigned*)p; p += (size_t)planes * GP;
        gH = (unsigned*)p; p += GH;
    }
    float4* egeom = (float4*)p;  p += EG;
    int*    esrcB = (int*)p;     p += ES;
    int*    rps   = (int*)p;     p += RP;
    int*    cnt   = (int*)p;     p += CF;
    int*    fill  = (int*)p;     p += CF;

    hipMemsetAsync(cnt,  0, CF, stream);
    hipMemsetAsync(fill, 0, CF, stream);
    if (planes) {
        hipMemsetAsync((char*)hA + (size_t)N_NODES*512, 0, 512, stream);
        hipMemsetAsync((char*)hB + (size_t)N_NODES*512, 0, 512, stream);
    }

    hist_k   <<<(N_EDGES+255)/256, 256, 0, stream>>>(dst, cnt);
    scan_k   <<<1, 1024, 0, stream>>>(cnt, rps);
    scatter_k<<<(N_EDGES+255)/256, 256, 0, stream>>>(coords, dst, src, rps, fill,
                                                     esrcB, egeom);
    pad_k    <<<(N_NODES+255)/256, 256, 0, stream>>>(rps, cnt, esrcB, egeom);
    if (planes) {
        geomh_k<<<(EPAD/8 + 255)/256, 256, 0, stream>>>(egeom, rps, gH);
        node_inM_k<<<(N_NODES/16 + 3)/4, 256, 0, stream>>>(x_dftb, W_in0, W_in1,
                                                           b_in, xA, hA);
    } else {
        node_in_k<<<N_NODES/4, 256, 0, stream>>>(x_dftb, W_in0, W_in1, b_in, xA,
                                                 nullptr);
    }
    if (planes == 3)
        gmatM_k<3><<<1536, 256, 0, stream>>>(egeom, W_basis, rps, Gm);

    float*  xo = xA; float*  xn = xB;
    half4v* ho = hA; half4v* hn = hB;
    for (int i = 0; i < 3; ++i) {
        if (planes) {
            if (planes == 1)
                gmatM_k<1><<<1536, 256, 0, stream>>>(egeom, W_basis + i*KK*FF, rps, Gm);
            const unsigned* Gp = Gm + ((planes == 3) ? (size_t)i*(EPAD/4)*64 : 0);
            if (i < 2)
                msg_pk_k<0><<<N_NODES/4, 256, 0, stream>>>(rps, esrcB, gH, Gp,
                                                           b_basis + i*FF, path_w + i*5*FF,
                                                           xo, ho, xn, hn,
                                                           nullptr, nullptr, nullptr, nullptr);
            else
                msg_pk_k<1><<<N_NODES/4, 256, 0, stream>>>(rps, esrcB, gH, Gp,
                                                           b_basis + i*FF, path_w + i*5*FF,
                                                           xo, ho, nullptr, nullptr,
                                                           W_out0, W_out1, b_out, out);
        } else {
            msg_slow_k<<<N_NODES/4, 256, 0, stream>>>(rps, cnt, esrcB, egeom,
                                                      W_basis + i*KK*FF,
                                                      b_basis + i*FF, path_w + i*5*FF,
                                                      xo, xn);
        }
        float*  tf = xo; xo = xn; xn = tf;
        half4v* th = ho; ho = hn; hn = th;
    }
    if (!planes)
        node_out_k<<<N_NODES/4, 256, 0, stream>>>(xo, W_out0, W_out1, b_out, out);
}

// Round 19
// 220.054 us; speedup vs baseline: 1.1045x; 1.1045x over previous
//
#include <hip/hip_runtime.h>

#define N_NODES 20000
#define N_EDGES 320000
#define FF 64
#define KK 32
#define EPAD 460032   // >= 320000 + 20000*7 (CSR padded to %8), multiple of 64
#define GT 64
#define BW 8

typedef _Float16 half4v __attribute__((ext_vector_type(4)));
typedef _Float16 h2 __attribute__((ext_vector_type(2)));
typedef short bf16x8 __attribute__((ext_vector_type(8)));
typedef float fx4 __attribute__((ext_vector_type(4)));

__device__ __forceinline__ unsigned short f2bf(float x) {
    unsigned u = __float_as_uint(x);
    unsigned r = (u + 0x7FFFu + ((u >> 16) & 1u)) >> 16;
    return (unsigned short)r;
}
__device__ __forceinline__ h2 u2h(unsigned u) {
    union { unsigned u; h2 h; } c; c.u = u; return c.h;
}
__device__ __forceinline__ unsigned h2u(h2 h) {
    union { h2 h; unsigned u; } c; c.h = h; return c.u;
}

__global__ __launch_bounds__(256) void hist_k(const int* __restrict__ dst,
                                              int* __restrict__ cnt) {
    int e = blockIdx.x * 256 + threadIdx.x;
    if (e >= N_EDGES) return;
    atomicAdd(&cnt[dst[e]], 1);
}

// Prefix-sum of PADDED counts (pad to %8): rps[n] = start, rps[N]=total padded.
__global__ __launch_bounds__(1024) void scan_k(const int* __restrict__ cnt,
                                               int* __restrict__ rps) {
    __shared__ int part[1024];
    int t = threadIdx.x;
    const int CH = 20;
    int lo = t * CH;
    int hi = lo + CH; if (hi > N_NODES) hi = N_NODES;
    int s = 0;
    for (int i = lo; i < hi && lo < N_NODES; ++i) s += (cnt[i] + 7) & ~7;
    if (lo >= N_NODES) s = 0;
    part[t] = s;
    __syncthreads();
    for (int off = 1; off < 1024; off <<= 1) {
        int tmp = (t >= off) ? part[t - off] : 0;
        __syncthreads();
        part[t] += tmp;
        __syncthreads();
    }
    int excl = part[t] - s;
    if (lo < N_NODES) {
        int run = excl;
        for (int i = lo; i < hi; ++i) { rps[i] = run; run += (cnt[i] + 7) & ~7; }
    }
    if (t == 1023) rps[N_NODES] = part[1023];
}

__global__ __launch_bounds__(256) void scatter_k(const float* __restrict__ coords,
                                                 const int* __restrict__ dst,
                                                 const int* __restrict__ src,
                                                 const int* __restrict__ rps,
                                                 int* __restrict__ fill,
                                                 int* __restrict__ esrcB,
                                                 float4* __restrict__ egeom) {
    int e = blockIdx.x * 256 + threadIdx.x;
    if (e >= N_EDGES) return;
    int di = dst[e], si = src[e];
    int pos = rps[di] + atomicAdd(&fill[di], 1);
    float rx = coords[di*3+0] - coords[si*3+0];
    float ry = coords[di*3+1] - coords[si*3+1];
    float rz = coords[di*3+2] - coords[si*3+2];
    float d = sqrtf(rx*rx + ry*ry + rz*rz + 1e-12f);
    float inv = 1.0f / d;
    esrcB[pos] = si * 512;
    egeom[pos] = make_float4(d, rx*inv, ry*inv, rz*inv);
}

// Fill padding holes with dummy edges -> zero row (A=0 => msg=0), finite geom.
__global__ __launch_bounds__(256) void pad_k(const int* __restrict__ rps,
                                             const int* __restrict__ cnt,
                                             int* __restrict__ esrcB,
                                             float4* __restrict__ egeom) {
    int n = blockIdx.x * 256 + threadIdx.x;
    if (n >= N_NODES) return;
    int fin = rps[n] + cnt[n];
    int stop = rps[n+1];
    for (int e = fin; e < stop; ++e) {
        esrcB[e] = N_NODES * 512;               // zero row
        egeom[e] = make_float4(1.f, 0.f, 0.f, 0.f);
    }
}

// Packed fp16 rhat plane, batch-major: per 8-edge batch b, 12 uints.
__global__ __launch_bounds__(256) void geomh_k(const float4* __restrict__ egeom,
                                               const int* __restrict__ rps,
                                               unsigned* __restrict__ gH) {
    int b = blockIdx.x * 256 + threadIdx.x;
    int total = rps[N_NODES];
    if (b * 8 >= total) return;
    float4 g[8];
    #pragma unroll
    for (int j = 0; j < 8; ++j) g[j] = egeom[b*8 + j];
    unsigned* o = gH + (size_t)b * 12;
    #pragma unroll
    for (int p = 0; p < 4; ++p) {
        h2 y; y[0] = (_Float16)g[2*p].y; y[1] = (_Float16)g[2*p+1].y;
        h2 z; z[0] = (_Float16)g[2*p].z; z[1] = (_Float16)g[2*p+1].z;
        h2 w; w[0] = (_Float16)g[2*p].w; w[1] = (_Float16)g[2*p+1].w;
        o[0*4 + p] = h2u(y);
        o[1*4 + p] = h2u(z);
        o[2*4 + p] = h2u(w);
    }
}

// MFMA gmat (R13-verified): G[64e][64f] = rbf x W, fp16 G4 packed 4 edges/word.
template<int NR>
__global__ __launch_bounds__(256) void gmatM_k(const float4* __restrict__ egeom,
                                               const float* __restrict__ Wb,
                                               const int* __restrict__ rps,
                                               half4v* __restrict__ G4) {
    __shared__ __align__(16) short WtL[NR*KK*FF];    // 12 KB bf16, k-major
    __shared__ __align__(16) short rbfL[2][GT*40];   // 2 x 5 KB, row pad 40
    int t = threadIdx.x;
    for (int idx = t; idx < NR*KK*FF; idx += 256)
        WtL[idx] = (short)f2bf(Wb[idx]);
    __syncthreads();

    int lane = t & 63, q = t >> 6;
    int kb = lane >> 4, cl = lane & 15;

    bf16x8 Bfr[NR][4];
    #pragma unroll
    for (int r = 0; r < NR; ++r) {
        #pragma unroll
        for (int nb = 0; nb < 4; ++nb) {
            bf16x8 fr;
            #pragma unroll
            for (int e2 = 0; e2 < 8; ++e2)
                fr[e2] = WtL[r*2048 + (kb*8 + e2)*64 + nb*16 + cl];
            Bfr[r][nb] = fr;
        }
    }

    int total = rps[N_NODES];
    int ntiles = (total + GT - 1) / GT;
    const float inv_w = 31.0f / 2.5f;
    int buf = 0;
    for (int tile = blockIdx.x; tile < ntiles; tile += gridDim.x) {
        int e0 = tile * GT;
        {
            int ew = t & 63;
            float d = egeom[e0 + ew].x;
            float t0 = d * inv_w;
            int k0 = (int)floorf(t0 + 0.5f) - 4;
            if (k0 < 0) k0 = 0;
            if (k0 > KK - 9) k0 = KK - 9;
            bf16x8 pk;
            #pragma unroll
            for (int i2 = 0; i2 < 8; ++i2) {
                int j = q*8 + i2;
                float dt = t0 - (float)j;
                float v = (j >= k0 && j < k0 + 9) ? __expf(-dt * dt) : 0.f;
                pk[i2] = (short)f2bf(v);
            }
            *(bf16x8*)(&rbfL[buf][ew*40 + q*8]) = pk;
        }
        __syncthreads();
        bf16x8 afr = *(const bf16x8*)(&rbfL[buf][(q*16 + cl)*40 + kb*8]);
        int eg = (e0 + q*16 + kb*4) >> 2;
        #pragma unroll
        for (int r = 0; r < NR; ++r) {
            #pragma unroll
            for (int nb = 0; nb < 4; ++nb) {
                fx4 dacc = {0.f, 0.f, 0.f, 0.f};
                dacc = __builtin_amdgcn_mfma_f32_16x16x32_bf16(afr, Bfr[r][nb],
                                                               dacc, 0, 0, 0);
                half4v hv;
                hv[0] = (_Float16)dacc[0]; hv[1] = (_Float16)dacc[1];
                hv[2] = (_Float16)dacc[2]; hv[3] = (_Float16)dacc[3];
                G4[(size_t)r*(EPAD/4)*64 + (size_t)eg*64 + nb*16 + cl] = hv;
            }
        }
        buf ^= 1;
    }
}

// MFMA node_in (R14-verified); fp16-only state output (no f32 x write).
__global__ __launch_bounds__(256) void node_inM_k(const float* __restrict__ x_dftb,
                                                  const float* __restrict__ W0,
                                                  const float* __restrict__ W1,
                                                  const float* __restrict__ bin,
                                                  half4v* __restrict__ xh) {
    int t = threadIdx.x;
    int q = t >> 6, lane = t & 63;
    int kb = lane >> 4, cl = lane & 15;
    int w = blockIdx.x * 4 + q;
    if (w >= N_NODES / 16) return;
    int n0 = w * 16;

    bf16x8 BF[2][4][2];
    #pragma unroll
    for (int cb = 0; cb < 4; ++cb) {
        #pragma unroll
        for (int kf = 0; kf < 2; ++kf) {
            bf16x8 f0, f1;
            #pragma unroll
            for (int j = 0; j < 8; ++j) {
                int k = kf*32 + kb*8 + j;
                f0[j] = (short)f2bf(W0[k*64 + cb*16 + cl]);
                f1[j] = (short)f2bf(W1[k*64 + cb*16 + cl]);
            }
            BF[0][cb][kf] = f0;
            BF[1][cb][kf] = f1;
        }
    }
    float bb[4];
    #pragma unroll
    for (int cb = 0; cb < 4; ++cb) bb[cb] = bin[cb*16 + cl];

    fx4 acc[4][4];   // [l][cb]
    #pragma unroll
    for (int l = 0; l < 4; ++l) {
        const float* xr = x_dftb + (size_t)(n0 + cl)*256 + l*64 + kb*8;
        float4 v0 = *(const float4*)(xr);
        float4 v1 = *(const float4*)(xr + 4);
        float4 v2 = *(const float4*)(xr + 32);
        float4 v3 = *(const float4*)(xr + 36);
        bf16x8 a0, a1;
        a0[0]=(short)f2bf(v0.x); a0[1]=(short)f2bf(v0.y);
        a0[2]=(short)f2bf(v0.z); a0[3]=(short)f2bf(v0.w);
        a0[4]=(short)f2bf(v1.x); a0[5]=(short)f2bf(v1.y);
        a0[6]=(short)f2bf(v1.z); a0[7]=(short)f2bf(v1.w);
        a1[0]=(short)f2bf(v2.x); a1[1]=(short)f2bf(v2.y);
        a1[2]=(short)f2bf(v2.z); a1[3]=(short)f2bf(v2.w);
        a1[4]=(short)f2bf(v3.x); a1[5]=(short)f2bf(v3.y);
        a1[6]=(short)f2bf(v3.z); a1[7]=(short)f2bf(v3.w);
        const int wsel = (l == 0) ? 0 : 1;
        #pragma unroll
        for (int cb = 0; cb < 4; ++cb) {
            fx4 c = {0.f, 0.f, 0.f, 0.f};
            c = __builtin_amdgcn_mfma_f32_16x16x32_bf16(a0, BF[wsel][cb][0], c, 0, 0, 0);
            c = __builtin_amdgcn_mfma_f32_16x16x32_bf16(a1, BF[wsel][cb][1], c, 0, 0, 0);
            acc[l][cb] = c;
        }
    }

    #pragma unroll
    for (int cb = 0; cb < 4; ++cb) {
        int f = cb*16 + cl;
        #pragma unroll
        for (int reg = 0; reg < 4; ++reg) {
            int n = n0 + kb*4 + reg;
            half4v hs;
            hs[0] = (_Float16)(acc[0][cb][reg] + bb[cb]);
            hs[1] = (_Float16)acc[1][cb][reg];
            hs[2] = (_Float16)acc[2][cb][reg];
            hs[3] = (_Float16)acc[3][cb][reg];
            xh[(size_t)n*64 + f] = hs;
        }
    }
}

// Scalar node_in (fallback path, f32 state).
__global__ __launch_bounds__(256) void node_in_k(const float* __restrict__ x_dftb,
                                                 const float* __restrict__ W0,
                                                 const float* __restrict__ W1,
                                                 const float* __restrict__ bin,
                                                 float* __restrict__ x) {
    int t = threadIdx.x;
    int q = t >> 6, f = t & 63;
    int n = blockIdx.x * 4 + q;
    float w0r[64], w1r[64];
    #pragma unroll
    for (int k = 0; k < 64; ++k) { w0r[k] = W0[k*64 + f]; w1r[k] = W1[k*64 + f]; }
    float a0 = bin[f], a1 = 0.f, a2 = 0.f, a3 = 0.f;
    const float4* xr = (const float4*)(x_dftb + (size_t)n * 256);
    #pragma unroll
    for (int j = 0; j < 16; ++j) {
        float4 x0 = xr[j];
        float4 x1 = xr[16 + j];
        float4 x2 = xr[32 + j];
        float4 x3 = xr[48 + j];
        a0 += x0.x*w0r[4*j] + x0.y*w0r[4*j+1] + x0.z*w0r[4*j+2] + x0.w*w0r[4*j+3];
        a1 += x1.x*w1r[4*j] + x1.y*w1r[4*j+1] + x1.z*w1r[4*j+2] + x1.w*w1r[4*j+3];
        a2 += x2.x*w1r[4*j] + x2.y*w1r[4*j+1] + x2.z*w1r[4*j+2] + x2.w*w1r[4*j+3];
        a3 += x3.x*w1r[4*j] + x3.y*w1r[4*j+1] + x3.z*w1r[4*j+2] + x3.w*w1r[4*j+3];
    }
    *(float4*)(x + (size_t)n*256 + f*4) = make_float4(a0, a1, a2, a3);
}

// One wave per dst node, lane = feature. Packed fp16 math (R16/R17 verified).
// fp16-only state: self read/write via xh; f32 accumulation inside.
// 16-edge batches + 8-edge remainder. LAST=1: fuse node_out.
template<int LAST>
__global__ __launch_bounds__(256) void msg_pk_k(const int* __restrict__ rps,
                                                const int* __restrict__ esrcB,
                                                const unsigned* __restrict__ gH,
                                                const half4v* __restrict__ G4,
                                                const float* __restrict__ bbv,
                                                const float* __restrict__ pw,
                                                const half4v* __restrict__ xo_h,
                                                half4v* __restrict__ xn_h,
                                                const float* __restrict__ Wo0,
                                                const float* __restrict__ Wo1,
                                                const float* __restrict__ bo,
                                                float* __restrict__ out) {
    int t = threadIdx.x;
    int q = t >> 6, f = t & 63;
    int n = blockIdx.x * 4 + q;

    half4v selfh = xo_h[(size_t)n*64 + f];
    float acc0 = (float)selfh[0], acc1 = (float)selfh[1];
    float acc2 = (float)selfh[2], acc3 = (float)selfh[3];

    float b_f = bbv[f];
    _Float16 bh = (_Float16)b_f;
    _Float16 p0h = (_Float16)pw[f],      p1h = (_Float16)pw[64+f];
    _Float16 p2h = (_Float16)pw[128+f],  p3h = (_Float16)pw[192+f];
    _Float16 p4h = (_Float16)pw[256+f];
    h2 pb;  pb[0]=bh;  pb[1]=bh;
    h2 pp0; pp0[0]=p0h; pp0[1]=p0h;
    h2 pp1; pp1[0]=p1h; pp1[1]=p1h;
    h2 pp2; pp2[0]=p2h; pp2[1]=p2h;
    h2 pp3; pp3[0]=p3h; pp3[1]=p3h;
    h2 pp4; pp4[0]=p4h; pp4[1]=p4h;

    const char* xob = (const char*)xo_h;
    int fb = f * 8;
    int beg = rps[n], end = rps[n+1];
    int e0 = beg;

    for (; e0 + 16 <= end; e0 += 16) {
        int4 o0 = *(const int4*)(esrcB + e0);
        int4 o1 = *(const int4*)(esrcB + e0 + 4);
        int4 o2 = *(const int4*)(esrcB + e0 + 8);
        int4 o3 = *(const int4*)(esrcB + e0 + 12);
        int off[16] = {o0.x,o0.y,o0.z,o0.w, o1.x,o1.y,o1.z,o1.w,
                       o2.x,o2.y,o2.z,o2.w, o3.x,o3.y,o3.z,o3.w};
        half4v h[16];
        #pragma unroll
        for (int j = 0; j < 16; ++j)
            h[j] = *(const half4v*)(xob + (size_t)(unsigned)off[j] + fb);
        uint2 ga = *(const uint2*)(G4 + (size_t)(e0 >> 2)*64 + f);
        uint2 gb = *(const uint2*)(G4 + (size_t)((e0 >> 2)+1)*64 + f);
        uint2 gc = *(const uint2*)(G4 + (size_t)((e0 >> 2)+2)*64 + f);
        uint2 gd = *(const uint2*)(G4 + (size_t)((e0 >> 2)+3)*64 + f);
        unsigned gpk[8] = {ga.x,ga.y,gb.x,gb.y,gc.x,gc.y,gd.x,gd.y};
        const unsigned* gb_ = gH + (size_t)(e0 >> 3) * 12;
        uint4 gy0 = *(const uint4*)(gb_);
        uint4 gz0 = *(const uint4*)(gb_ + 4);
        uint4 gw0 = *(const uint4*)(gb_ + 8);
        uint4 gy1 = *(const uint4*)(gb_ + 12);
        uint4 gz1 = *(const uint4*)(gb_ + 16);
        uint4 gw1 = *(const uint4*)(gb_ + 20);
        unsigned gyu[8] = {gy0.x,gy0.y,gy0.z,gy0.w, gy1.x,gy1.y,gy1.z,gy1.w};
        unsigned gzu[8] = {gz0.x,gz0.y,gz0.z,gz0.w, gz1.x,gz1.y,gz1.z,gz1.w};
        unsigned gwu[8] = {gw0.x,gw0.y,gw0.z,gw0.w, gw1.x,gw1.y,gw1.z,gw1.w};

        h2 s0, s1, s2, s3;
        s0[0]=(_Float16)0; s0[1]=(_Float16)0; s1 = s0; s2 = s0; s3 = s0;

        #pragma unroll
        for (int i = 0; i < 8; ++i) {
            h2 a0; a0[0] = h[2*i][0]; a0[1] = h[2*i+1][0];
            h2 a1; a1[0] = h[2*i][1]; a1[1] = h[2*i+1][1];
            h2 a2; a2[0] = h[2*i][2]; a2[1] = h[2*i+1][2];
            h2 a3; a3[0] = h[2*i][3]; a3[1] = h[2*i+1][3];
            h2 G  = u2h(gpk[i]);
            h2 ry = u2h(gyu[i]);
            h2 rz = u2h(gzu[i]);
            h2 rw = u2h(gwu[i]);

            h2 g0v = G + pb;
            h2 dot = a1*ry + a2*rz + a3*rw;
            s0 += pp0*a0*g0v + pp1*dot*G;
            h2 tA = pp2*a0*G;
            h2 tB = pp3*g0v;
            h2 tC = pp4*G;
            s1 += tA*ry + tB*a1 + tC*(a2*rw - a3*rz);
            s2 += tA*rz + tB*a2 + tC*(a3*ry - a1*rw);
            s3 += tA*rw + tB*a3 + tC*(a1*rz - a2*ry);
        }
        acc0 += (float)s0[0] + (float)s0[1];
        acc1 += (float)s1[0] + (float)s1[1];
        acc2 += (float)s2[0] + (float)s2[1];
        acc3 += (float)s3[0] + (float)s3[1];
    }

    if (e0 < end) {
        int4 oa = *(const int4*)(esrcB + e0);
        int4 ob = *(const int4*)(esrcB + e0 + 4);
        int off[BW] = {oa.x, oa.y, oa.z, oa.w, ob.x, ob.y, ob.z, ob.w};
        half4v h[BW];
        #pragma unroll
        for (int j = 0; j < BW; ++j)
            h[j] = *(const half4v*)(xob + (size_t)(unsigned)off[j] + fb);
        uint2 gau = *(const uint2*)(G4 + (size_t)(e0 >> 2)*64 + f);
        uint2 gbu = *(const uint2*)(G4 + (size_t)((e0 >> 2) + 1)*64 + f);
        unsigned gpk[4] = {gau.x, gau.y, gbu.x, gbu.y};
        const unsigned* gb_ = gH + (size_t)(e0 >> 3) * 12;
        uint4 gyv = *(const uint4*)(gb_);
        uint4 gzv = *(const uint4*)(gb_ + 4);
        uint4 gwv = *(const uint4*)(gb_ + 8);
        unsigned gyu[4] = {gyv.x, gyv.y, gyv.z, gyv.w};
        unsigned gzu[4] = {gzv.x, gzv.y, gzv.z, gzv.w};
        unsigned gwu[4] = {gwv.x, gwv.y, gwv.z, gwv.w};

        h2 s0, s1, s2, s3;
        s0[0]=(_Float16)0; s0[1]=(_Float16)0; s1 = s0; s2 = s0; s3 = s0;

        #pragma unroll
        for (int i = 0; i < 4; ++i) {
            h2 a0; a0[0] = h[2*i][0]; a0[1] = h[2*i+1][0];
            h2 a1; a1[0] = h[2*i][1]; a1[1] = h[2*i+1][1];
            h2 a2; a2[0] = h[2*i][2]; a2[1] = h[2*i+1][2];
            h2 a3; a3[0] = h[2*i][3]; a3[1] = h[2*i+1][3];
            h2 G  = u2h(gpk[i]);
            h2 ry = u2h(gyu[i]);
            h2 rz = u2h(gzu[i]);
            h2 rw = u2h(gwu[i]);

            h2 g0v = G + pb;
            h2 dot = a1*ry + a2*rz + a3*rw;
            s0 += pp0*a0*g0v + pp1*dot*G;
            h2 tA = pp2*a0*G;
            h2 tB = pp3*g0v;
            h2 tC = pp4*G;
            s1 += tA*ry + tB*a1 + tC*(a2*rw - a3*rz);
            s2 += tA*rz + tB*a2 + tC*(a3*ry - a1*rw);
            s3 += tA*rw + tB*a3 + tC*(a1*rz - a2*ry);
        }
        acc0 += (float)s0[0] + (float)s0[1];
        acc1 += (float)s1[0] + (float)s1[1];
        acc2 += (float)s2[0] + (float)s2[1];
        acc3 += (float)s3[0] + (float)s3[1];
    }

    if (LAST) {
        float w0 = Wo0[f], w1 = Wo1[f];
        float s0 = acc0 * w0, s1 = acc1 * w1, s2 = acc2 * w1, s3 = acc3 * w1;
        #pragma unroll
        for (int off2 = 32; off2 >= 1; off2 >>= 1) {
            s0 += __shfl_down(s0, off2, 64);
            s1 += __shfl_down(s1, off2, 64);
            s2 += __shfl_down(s2, off2, 64);
            s3 += __shfl_down(s3, off2, 64);
        }
        if (f == 0) {
            float b = bo[0];
            out[n*4 + 0] = s0 + b;
            out[n*4 + 1] = s1;
            out[n*4 + 2] = s2;
            out[n*4 + 3] = s3;
        }
    } else {
        half4v hs;
        hs[0] = (_Float16)acc0; hs[1] = (_Float16)acc1;
        hs[2] = (_Float16)acc2; hs[3] = (_Float16)acc3;
        xn_h[(size_t)n*64 + f] = hs;
    }
}

// Fallback (tiny ws): f32 gathers, in-kernel shfl G, real-count loop.
__global__ __launch_bounds__(256) void msg_slow_k(const int* __restrict__ rps,
                                                  const int* __restrict__ cnt,
                                                  const int* __restrict__ esrcB,
                                                  const float4* __restrict__ egeom,
                                                  const float* __restrict__ Wb,
                                                  const float* __restrict__ bbv,
                                                  const float* __restrict__ pw,
                                                  const float* __restrict__ xo_f,
                                                  float* __restrict__ xn_f) {
    int t = threadIdx.x;
    int n = blockIdx.x * 4 + (t >> 6);
    int f = t & 63;
    float wreg[KK];
    #pragma unroll
    for (int k = 0; k < KK; ++k) wreg[k] = Wb[k*64 + f];
    float4 self = *(const float4*)(xo_f + (size_t)n*256 + f*4);
    float acc0 = self.x, acc1 = self.y, acc2 = self.z, acc3 = self.w;
    float b_f = bbv[f];
    float p0 = pw[f], p1 = pw[64+f], p2 = pw[128+f], p3 = pw[192+f], p4 = pw[256+f];
    const float wdt = 2.5f / 31.0f, inv_w = 31.0f / 2.5f;
    float ck = wdt * (float)(f & 31);
    int beg = rps[n], end = beg + cnt[n];
    const char* xob = (const char*)xo_f;
    for (int e = beg; e < end; ++e) {
        int off = esrcB[e];
        float4 g4 = egeom[e];
        float4 v = *(const float4*)(xob + ((size_t)(unsigned)off << 1) + f*16);
        float tt = (g4.x - ck) * inv_w;
        float my_rbf = __expf(-tt * tt);
        float Gs = 0.f;
        #pragma unroll
        for (int k = 0; k < KK; ++k) Gs += __shfl(my_rbf, k, 64) * wreg[k];
        float g0v = Gs + b_f;
        float dotav = v.y*g4.y + v.z*g4.z + v.w*g4.w;
        acc0 += p0*v.x*g0v + p1*dotav*Gs;
        float tA = p2*v.x*Gs, tB = p3*g0v, tC = p4*Gs;
        acc1 += tA*g4.y + tB*v.y + tC*(v.z*g4.w - v.w*g4.z);
        acc2 += tA*g4.z + tB*v.z + tC*(v.w*g4.y - v.y*g4.w);
        acc3 += tA*g4.w + tB*v.w + tC*(v.y*g4.z - v.z*g4.y);
    }
    *(float4*)(xn_f + (size_t)n*256 + f*4) = make_float4(acc0, acc1, acc2, acc3);
}

__global__ __launch_bounds__(256) void node_out_k(const float* __restrict__ x,
                                                  const float* __restrict__ W0,
                                                  const float* __restrict__ W1,
                                                  const float* __restrict__ bout,
                                                  float* __restrict__ out) {
    int n = blockIdx.x * 4 + (threadIdx.x >> 6);
    int f = threadIdx.x & 63;
    float w0 = W0[f], w1 = W1[f];
    float4 v = *(const float4*)(x + (size_t)n*256 + f*4);
    float s0 = v.x * w0, s1 = v.y * w1, s2 = v.z * w1, s3 = v.w * w1;
    #pragma unroll
    for (int off = 32; off >= 1; off >>= 1) {
        s0 += __shfl_down(s0, off, 64);
        s1 += __shfl_down(s1, off, 64);
        s2 += __shfl_down(s2, off, 64);
        s3 += __shfl_down(s3, off, 64);
    }
    if (f == 0) {
        float b = bout[0];
        out[n*4 + 0] = s0 + b;
        out[n*4 + 1] = s1;
        out[n*4 + 2] = s2;
        out[n*4 + 3] = s3;
    }
}

extern "C" void kernel_launch(void* const* d_in, const int* in_sizes, int n_in,
                              void* d_out, int out_size, void* d_ws, size_t ws_size,
                              hipStream_t stream) {
    const float* x_dftb  = (const float*)d_in[0];
    const float* coords  = (const float*)d_in[1];
    const int*   dst     = (const int*)  d_in[2];
    const int*   src     = (const int*)  d_in[3];
    const float* W_in0   = (const float*)d_in[4];
    const float* W_in1   = (const float*)d_in[5];
    const float* b_in    = (const float*)d_in[6];
    const float* W_basis = (const float*)d_in[7];
    const float* b_basis = (const float*)d_in[8];
    const float* path_w  = (const float*)d_in[9];
    const float* W_out0  = (const float*)d_in[10];
    const float* W_out1  = (const float*)d_in[11];
    const float* b_out   = (const float*)d_in[12];
    float* out = (float*)d_out;

    const size_t XF = (size_t)N_NODES * 256 * 4;        // 20.48 MB (fallback only)
    const size_t XH = (size_t)(N_NODES + 1) * 64 * 8;   // 10.24 MB (fp16 + zero row)
    const size_t EG = (size_t)EPAD * 16;                //  7.36 MB
    const size_t ES = (size_t)EPAD * 4;                 //  1.84 MB
    const size_t GP = (size_t)EPAD * 64 * 2;            // 58.88 MB (one fp16 plane)
    const size_t GH = (size_t)(EPAD/8) * 48;            //  2.76 MB (packed rhat)
    const size_t RP = (((size_t)(N_NODES + 1) * 4) + 15) & ~(size_t)15;
    const size_t CF = (size_t)N_NODES * 4;

    const size_t base_need = 2*XH + EG + ES + GH + RP + 2*CF;
    int planes = (ws_size >= base_need + 3*GP) ? 3
               : (ws_size >= base_need + 1*GP) ? 1 : 0;

    char* p = (char*)d_ws;
    half4v*  hA = nullptr; half4v* hB = nullptr;
    half4v*  Gm = nullptr;
    unsigned* gH = nullptr;
    float* xA = nullptr; float* xB = nullptr;
    if (planes) {
        hA = (half4v*)p;  p += XH;
        hB = (half4v*)p;  p += XH;
        Gm = (half4v*)p;  p += (size_t)planes * GP;
        gH = (unsigned*)p; p += GH;
    } else {
        xA = (float*)p;   p += XF;
        xB = (float*)p;   p += XF;
    }
    float4* egeom = (float4*)p;  p += EG;
    int*    esrcB = (int*)p;     p += ES;
    int*    rps   = (int*)p;     p += RP;
    int*    cnt   = (int*)p;     p += CF;
    int*    fill  = (int*)p;     p += CF;

    hipMemsetAsync(cnt,  0, CF, stream);
    hipMemsetAsync(fill, 0, CF, stream);
    if (planes) {
        hipMemsetAsync((char*)hA + (size_t)N_NODES*512, 0, 512, stream);
        hipMemsetAsync((char*)hB + (size_t)N_NODES*512, 0, 512, stream);
    }

    hist_k   <<<(N_EDGES+255)/256, 256, 0, stream>>>(dst, cnt);
    scan_k   <<<1, 1024, 0, stream>>>(cnt, rps);
    scatter_k<<<(N_EDGES+255)/256, 256, 0, stream>>>(coords, dst, src, rps, fill,
                                                     esrcB, egeom);
    pad_k    <<<(N_NODES+255)/256, 256, 0, stream>>>(rps, cnt, esrcB, egeom);
    if (planes) {
        geomh_k<<<(EPAD/8 + 255)/256, 256, 0, stream>>>(egeom, rps, gH);
        node_inM_k<<<(N_NODES/16 + 3)/4, 256, 0, stream>>>(x_dftb, W_in0, W_in1,
                                                           b_in, hA);
        if (planes == 3)
            gmatM_k<3><<<1536, 256, 0, stream>>>(egeom, W_basis, rps, Gm);

        half4v* ho = hA; half4v* hn = hB;
        for (int i = 0; i < 3; ++i) {
            if (planes == 1)
                gmatM_k<1><<<1536, 256, 0, stream>>>(egeom, W_basis + i*KK*FF, rps, Gm);
            const half4v* Gp = Gm + ((planes == 3) ? (size_t)i*(EPAD/4)*64 : 0);
            if (i < 2)
                msg_pk_k<0><<<N_NODES/4, 256, 0, stream>>>(rps, esrcB, gH, Gp,
                                                           b_basis + i*FF, path_w + i*5*FF,
                                                           ho, hn,
                                                           nullptr, nullptr, nullptr, nullptr);
            else
                msg_pk_k<1><<<N_NODES/4, 256, 0, stream>>>(rps, esrcB, gH, Gp,
                                                           b_basis + i*FF, path_w + i*5*FF,
                                                           ho, nullptr,
                                                           W_out0, W_out1, b_out, out);
            half4v* th = ho; ho = hn; hn = th;
        }
    } else {
        node_in_k<<<N_NODES/4, 256, 0, stream>>>(x_dftb, W_in0, W_in1, b_in, xA);
        float* xo = xA; float* xn = xB;
        for (int i = 0; i < 3; ++i) {
            msg_slow_k<<<N_NODES/4, 256, 0, stream>>>(rps, cnt, esrcB, egeom,
                                                      W_basis + i*KK*FF,
                                                      b_basis + i*FF, path_w + i*5*FF,
                                                      xo, xn);
            float* tf = xo; xo = xn; xn = tf;
        }
        node_out_k<<<N_NODES/4, 256, 0, stream>>>(xo, W_out0, W_out1, b_out, out);
    }
}